// Round 4
// baseline (3226.210 us; speedup 1.0000x reference)
//
#include <hip/hip_runtime.h>
#include <hip/hip_bf16.h>
#include <cstdint>
#include <math.h>

typedef __attribute__((ext_vector_type(4))) float f32x4;
typedef __attribute__((ext_vector_type(8))) __bf16 bf16x8;

__device__ __forceinline__ unsigned short f2bf(float f) {
    union { float f; unsigned u; } v; v.f = f;
    unsigned u = v.u + 0x7fffu + ((v.u >> 16) & 1u);
    return (unsigned short)(u >> 16);
}

__device__ __forceinline__ float gelu_tanh(float x) {
    float x3 = x * x * x;
    float t = tanhf(0.7978845608028654f * (x + 0.044715f * x3));
    return 0.5f * x * (1.0f + t);
}

__device__ __forceinline__ void gload_lds16(const void* g, void* l) {
    __builtin_amdgcn_global_load_lds(
        (__attribute__((address_space(1))) void*)(uintptr_t)g,
        (__attribute__((address_space(3))) void*)(unsigned)(uintptr_t)l,
        16, 0, 0);
}

// ---------------- fused bias-add + residual + LayerNorm ----------------
__global__ __launch_bounds__(256)
void fused_add_ln(const float* __restrict__ in, const float* __restrict__ res,
                  const float* __restrict__ bias, const float* __restrict__ nw,
                  const float* __restrict__ nb, float* __restrict__ resadd,
                  unsigned short* __restrict__ lnout, int H) {
    const int row = blockIdx.x;
    const int tid = threadIdx.x;
    const size_t base = (size_t)row * H;
    float v[16];
    float s = 0.f, ss = 0.f;
#pragma unroll
    for (int i = 0; i < 4; ++i) {
        int idx = (i * 256 + tid) * 4;
        float4 a = *(const float4*)(in + base + idx);
        float4 b = *(const float4*)(res + base + idx);
        float4 c = *(const float4*)(bias + idx);
        float x0 = a.x + b.x + c.x, x1 = a.y + b.y + c.y;
        float x2 = a.z + b.z + c.z, x3 = a.w + b.w + c.w;
        v[i * 4 + 0] = x0; v[i * 4 + 1] = x1; v[i * 4 + 2] = x2; v[i * 4 + 3] = x3;
        s += x0 + x1 + x2 + x3;
        ss += x0 * x0 + x1 * x1 + x2 * x2 + x3 * x3;
    }
#pragma unroll
    for (int off = 32; off > 0; off >>= 1) {
        s += __shfl_down(s, off);
        ss += __shfl_down(ss, off);
    }
    __shared__ float red[8];
    const int w = tid >> 6;
    if ((tid & 63) == 0) { red[w] = s; red[4 + w] = ss; }
    __syncthreads();
    s = red[0] + red[1] + red[2] + red[3];
    ss = red[4] + red[5] + red[6] + red[7];
    const float mean = s / H;
    const float var = ss / H - mean * mean;
    const float rstd = rsqrtf(var + 1e-12f);
#pragma unroll
    for (int i = 0; i < 4; ++i) {
        int idx = (i * 256 + tid) * 4;
        float4 wv = *(const float4*)(nw + idx);
        float4 bv = *(const float4*)(nb + idx);
        float4 r;
        r.x = v[i * 4 + 0]; r.y = v[i * 4 + 1]; r.z = v[i * 4 + 2]; r.w = v[i * 4 + 3];
        *(float4*)(resadd + base + idx) = r;
        ushort4 o;
        o.x = f2bf((r.x - mean) * rstd * wv.x + bv.x);
        o.y = f2bf((r.y - mean) * rstd * wv.y + bv.y);
        o.z = f2bf((r.z - mean) * rstd * wv.z + bv.z);
        o.w = f2bf((r.w - mean) * rstd * wv.w + bv.w);
        *(ushort4*)(lnout + base + idx) = o;
    }
}

// ---------------- fp32 -> bf16 weight cast ----------------
__global__ __launch_bounds__(256)
void cast_w(const float* __restrict__ w, unsigned short* __restrict__ o, long long n4) {
    long long i = (long long)blockIdx.x * 256 + threadIdx.x;
    if (i >= n4) return;
    float4 f = *(const float4*)(w + i * 4);
    ushort4 u;
    u.x = f2bf(f.x); u.y = f2bf(f.y); u.z = f2bf(f.z); u.w = f2bf(f.w);
    *(ushort4*)(o + i * 4) = u;
}

// ---------------- 256x256 bf16 GEMM, C = A * B^T, 8-phase read-ahead ----
// 512 threads = 8 waves (2M x 4N), per-wave 128x64 output.
// LDS 128 KiB: [slot][A/B][half 128 rows][64 cols] bf16, slot = tile & 1.
// 2 K-tiles per iteration, 8 phases. Phase p: {ds_reads for MFMA[p+1];
// stage 1 half-tile (2 gloads); [vmcnt(4) @ p4,p8]; s_barrier; setprio(1);
// 16 MFMA consuming phase p-1's reads; setprio(0)}. Reads cross one barrier
// before use -> LDS latency hidden under previous MFMA cluster + barrier.
// Stage order p1..8: A0(T1) A1(T1) B0(T0+2) B1(T0+2) A0(T0+2) A1(T0+2)
// B0(T1+2) B1(T1+2). Clobber-safety: every staged region is barrier-
// separated from its last ds_read (B regions read only at p1/p5; A regions
// last read at p4/p8). Deadlines: vmcnt(4) leaves exactly the 2 newest
// halves in flight; everything needed by the next 4 phases has landed.
// Pipeline fill: 6-half prologue + zero-operand MFMA at iter0-p1.
// Drain: peeled last iteration, vmcnt(0) @ p4, trailing q3 MFMA.
#define GBM 256
#define GBN 256
#define GBK 64

#define STAGE(s, mat, h, T) do {                                              \
    const unsigned short* _src = ((mat) ? pB : pA)                            \
        + (size_t)((h) * 128) * K + (size_t)(T) * 64;                         \
    char* _dst = ldsc + (s) * 65536 + (mat) * 32768 + (h) * 16384 + dOff;     \
    gload_lds16(_src, _dst);                                                  \
    gload_lds16(_src + (size_t)64 * K, _dst + 8192);                          \
} while (0)

#define RD_B(tb, s) do {                                                      \
    _Pragma("unroll")                                                         \
    for (int ni = 0; ni < 4; ++ni)                                            \
        _Pragma("unroll")                                                     \
        for (int kk = 0; kk < 2; ++kk)                                        \
            bq[tb][ni][kk] = *(const bf16x8*)(ldsc + (s) * 65536 + 32768      \
                + ((wc * 64 + ni * 16 + lrow) << 7) + ckk[kk]);               \
} while (0)

#define RD_A(ab, q, s) do {                                                   \
    _Pragma("unroll")                                                         \
    for (int m2 = 0; m2 < 2; ++m2)                                            \
        _Pragma("unroll")                                                     \
        for (int kk = 0; kk < 2; ++kk)                                        \
            aq[ab][m2][kk] = *(const bf16x8*)(ldsc + (s) * 65536              \
                + ((wr * 128 + ((q) * 2 + m2) * 16 + lrow) << 7) + ckk[kk]);  \
} while (0)

#define MF(q, ab, tb) do {                                                    \
    __builtin_amdgcn_s_setprio(1);                                            \
    _Pragma("unroll")                                                         \
    for (int m2 = 0; m2 < 2; ++m2)                                            \
        _Pragma("unroll")                                                     \
        for (int ni = 0; ni < 4; ++ni)                                        \
            _Pragma("unroll")                                                 \
            for (int kk = 0; kk < 2; ++kk)                                    \
                acc[(q) * 2 + m2][ni] = __builtin_amdgcn_mfma_f32_16x16x32_bf16( \
                    aq[ab][m2][kk], bq[tb][ni][kk], acc[(q) * 2 + m2][ni], 0, 0, 0); \
    __builtin_amdgcn_s_setprio(0);                                            \
} while (0)

#define BAR do { asm volatile("s_barrier" ::: "memory");                      \
                 __builtin_amdgcn_sched_barrier(0); } while (0)
#define GATE4 asm volatile("s_waitcnt vmcnt(4)" ::: "memory")
#define GATE0 asm volatile("s_waitcnt vmcnt(0)" ::: "memory")

template <int EPI>
__global__ __launch_bounds__(512, 2)
void gemm256(const unsigned short* __restrict__ A,
             const unsigned short* __restrict__ B,
             const float* __restrict__ bias_n,
             const float* __restrict__ resadd,
             void* __restrict__ Cout,
             int M, int N, int K) {
    __shared__ unsigned short lds[2][2][2][128 * 64];
    char* ldsc = (char*)&lds[0][0][0][0];
    const int tid = threadIdx.x;
    const int lane = tid & 63;
    const int w = tid >> 6;
    const int wr = w >> 2;   // 0..1
    const int wc = w & 3;    // 0..3

    const int nwg = gridDim.x;
    const int lg = (blockIdx.x & 7) * (nwg >> 3) + (blockIdx.x >> 3);
    const int nbx = N / GBN;
    const int brow = lg / nbx;
    const int bcol = lg % nbx;

    // staging source (pre-swizzled so linear LDS write = swizzled layout)
    const int srow = tid >> 3;                                   // 0..63
    const int scol = ((((tid & 7) << 4) ^ ((srow & 7) << 4)) >> 1);
    const unsigned short* pA = A + (size_t)(brow * GBM + srow) * K + scol;
    const unsigned short* pB = B + (size_t)(bcol * GBN + srow) * K + scol;
    const int dOff = tid * 16;

    // ds_read column bytes (swizzled), constant per lane
    const int lrow = lane & 15;
    int ckk[2];
    ckk[0] = (((lane >> 4) << 4)) ^ ((lrow & 7) << 4);
    ckk[1] = ckk[0] ^ 64;

    f32x4 acc[8][4] = {};
    bf16x8 aq[2][2][2];   // [bank][m2][kk]
    bf16x8 bq[2][4][2];   // [tile-parity][ni][kk]
    {
        bf16x8 z = {};
#pragma unroll
        for (int m2 = 0; m2 < 2; ++m2)
#pragma unroll
            for (int kk = 0; kk < 2; ++kk) aq[0][m2][kk] = z;
#pragma unroll
        for (int ni = 0; ni < 4; ++ni)
#pragma unroll
            for (int kk = 0; kk < 2; ++kk) bq[1][ni][kk] = z;
    }

    const int NT = K / GBK;
    const int niter = NT / 2;

    // prologue: tile0 (B0,B1,A0,A1) + tile1 (B0,B1); first 8 loads gated
    STAGE(0, 1, 0, 0); STAGE(0, 1, 1, 0);
    STAGE(0, 0, 0, 0); STAGE(0, 0, 1, 0);
    STAGE(1, 1, 0, 1); STAGE(1, 1, 1, 1);
    GATE4;
    BAR;

    for (int i = 0; i < niter - 1; ++i) {
        const int T0 = 2 * i, T1 = 2 * i + 1;
        // p1
        RD_B(0, 0); RD_A(1, 0, 0); STAGE(1, 0, 0, T1);           BAR; MF(3, 0, 1);
        // p2
        RD_A(0, 1, 0);              STAGE(1, 0, 1, T1);          BAR; MF(0, 1, 0);
        // p3
        RD_A(1, 2, 0);              STAGE(0, 1, 0, T0 + 2);      BAR; MF(1, 0, 0);
        // p4
        RD_A(0, 3, 0);              STAGE(0, 1, 1, T0 + 2); GATE4; BAR; MF(2, 1, 0);
        // p5
        RD_B(1, 1); RD_A(1, 0, 1);  STAGE(0, 0, 0, T0 + 2);      BAR; MF(3, 0, 0);
        // p6
        RD_A(0, 1, 1);              STAGE(0, 0, 1, T0 + 2);      BAR; MF(0, 1, 1);
        // p7
        RD_A(1, 2, 1);              STAGE(1, 1, 0, T1 + 2);      BAR; MF(1, 0, 1);
        // p8
        RD_A(0, 3, 1);              STAGE(1, 1, 1, T1 + 2); GATE4; BAR; MF(2, 1, 1);
    }
    {   // peeled final iteration (tiles NT-2, NT-1)
        const int T1 = NT - 1;
        RD_B(0, 0); RD_A(1, 0, 0); STAGE(1, 0, 0, T1);           BAR; MF(3, 0, 1);
        RD_A(0, 1, 0);              STAGE(1, 0, 1, T1);          BAR; MF(0, 1, 0);
        RD_A(1, 2, 0);                                           BAR; MF(1, 0, 0);
        RD_A(0, 3, 0);                                     GATE0; BAR; MF(2, 1, 0);
        RD_B(1, 1); RD_A(1, 0, 1);                               BAR; MF(3, 0, 0);
        RD_A(0, 1, 1);                                           BAR; MF(0, 1, 1);
        RD_A(1, 2, 1);                                           BAR; MF(1, 0, 1);
        RD_A(0, 3, 1);                                           BAR; MF(2, 1, 1);
        MF(3, 0, 1);  // trailing q3 of tile NT-1
    }

    // epilogue: C/D layout col = lane&15, row = (lane>>4)*4 + j
    const int c0 = bcol * GBN + wc * 64 + lrow;
    const int r0 = brow * GBM + wr * 128 + (lane >> 4) * 4;
#pragma unroll
    for (int mi = 0; mi < 8; ++mi) {
#pragma unroll
        for (int j = 0; j < 4; ++j) {
            const int row = r0 + mi * 16 + j;
#pragma unroll
            for (int ni = 0; ni < 4; ++ni) {
                const int col = c0 + ni * 16;
                float x = acc[mi][ni][j] + bias_n[col];
                if (EPI == 0) {
                    ((unsigned short*)Cout)[(size_t)row * N + col] = f2bf(gelu_tanh(x));
                } else {
                    const size_t off = (size_t)row * N + col;
                    ((float*)Cout)[off] = x + resadd[off];
                }
            }
        }
    }
}

extern "C" void kernel_launch(void* const* d_in, const int* in_sizes, int n_in,
                              void* d_out, int out_size, void* d_ws, size_t ws_size,
                              hipStream_t stream) {
    const float* input    = (const float*)d_in[0];
    const float* residual = (const float*)d_in[1];
    const float* bias     = (const float*)d_in[2];
    const float* attn_nw  = (const float*)d_in[3];
    const float* attn_nb  = (const float*)d_in[4];
    const float* inter_w  = (const float*)d_in[5];
    const float* inter_b  = (const float*)d_in[6];
    const float* output_w = (const float*)d_in[7];
    const float* output_b = (const float*)d_in[8];

    const int H = in_sizes[3];            // 4096
    const int I = in_sizes[6];            // 16384
    const int T = in_sizes[0] / H;        // B*S = 4096

    char* ws = (char*)d_ws;
    float* resadd      = (float*)ws;
    unsigned short* ln = (unsigned short*)(ws + (size_t)T * H * 4);
    unsigned short* w1 = (unsigned short*)((char*)ln + (size_t)T * H * 2);
    unsigned short* w2 = w1 + (size_t)I * H;
    unsigned short* act = w2 + (size_t)H * I;

    fused_add_ln<<<T, 256, 0, stream>>>(input, residual, bias, attn_nw, attn_nb,
                                        resadd, ln, H);

    {
        long long n4 = (long long)I * H / 4;
        int blocks = (int)((n4 + 255) / 256);
        cast_w<<<blocks, 256, 0, stream>>>(inter_w, w1, n4);
        cast_w<<<blocks, 256, 0, stream>>>(output_w, w2, n4);
    }

    // GEMM1: act = gelu(ln @ inter_w^T + inter_b)   [T,I]
    {
        dim3 grid((T / GBM) * (I / GBN));
        gemm256<0><<<grid, 512, 0, stream>>>(ln, w1, inter_b, nullptr, act, T, I, H);
    }

    // GEMM2: out = act @ output_w^T + output_b + resadd   [T,H]
    {
        dim3 grid((T / GBM) * (H / GBN));
        gemm256<1><<<grid, 512, 0, stream>>>(act, w2, output_b, resadd, d_out, T, H, I);
    }
}

// Round 5
// 3224.857 us; speedup vs baseline: 1.0004x; 1.0004x over previous
//
#include <hip/hip_runtime.h>
#include <hip/hip_bf16.h>
#include <cstdint>
#include <math.h>

typedef __attribute__((ext_vector_type(4))) float f32x4;
typedef __attribute__((ext_vector_type(8))) __bf16 bf16x8;

__device__ __forceinline__ unsigned short f2bf(float f) {
    union { float f; unsigned u; } v; v.f = f;
    unsigned u = v.u + 0x7fffu + ((v.u >> 16) & 1u);
    return (unsigned short)(u >> 16);
}

__device__ __forceinline__ float gelu_tanh(float x) {
    float x3 = x * x * x;
    float t = tanhf(0.7978845608028654f * (x + 0.044715f * x3));
    return 0.5f * x * (1.0f + t);
}

__device__ __forceinline__ void gload_lds16(const void* g, void* l) {
    __builtin_amdgcn_global_load_lds(
        (__attribute__((address_space(1))) void*)(uintptr_t)g,
        (__attribute__((address_space(3))) void*)(unsigned)(uintptr_t)l,
        16, 0, 0);
}

// ---------------- fused bias-add + residual + LayerNorm ----------------
__global__ __launch_bounds__(256)
void fused_add_ln(const float* __restrict__ in, const float* __restrict__ res,
                  const float* __restrict__ bias, const float* __restrict__ nw,
                  const float* __restrict__ nb, float* __restrict__ resadd,
                  unsigned short* __restrict__ lnout, int H) {
    const int row = blockIdx.x;
    const int tid = threadIdx.x;
    const size_t base = (size_t)row * H;
    float v[16];
    float s = 0.f, ss = 0.f;
#pragma unroll
    for (int i = 0; i < 4; ++i) {
        int idx = (i * 256 + tid) * 4;
        float4 a = *(const float4*)(in + base + idx);
        float4 b = *(const float4*)(res + base + idx);
        float4 c = *(const float4*)(bias + idx);
        float x0 = a.x + b.x + c.x, x1 = a.y + b.y + c.y;
        float x2 = a.z + b.z + c.z, x3 = a.w + b.w + c.w;
        v[i * 4 + 0] = x0; v[i * 4 + 1] = x1; v[i * 4 + 2] = x2; v[i * 4 + 3] = x3;
        s += x0 + x1 + x2 + x3;
        ss += x0 * x0 + x1 * x1 + x2 * x2 + x3 * x3;
    }
#pragma unroll
    for (int off = 32; off > 0; off >>= 1) {
        s += __shfl_down(s, off);
        ss += __shfl_down(ss, off);
    }
    __shared__ float red[8];
    const int w = tid >> 6;
    if ((tid & 63) == 0) { red[w] = s; red[4 + w] = ss; }
    __syncthreads();
    s = red[0] + red[1] + red[2] + red[3];
    ss = red[4] + red[5] + red[6] + red[7];
    const float mean = s / H;
    const float var = ss / H - mean * mean;
    const float rstd = rsqrtf(var + 1e-12f);
#pragma unroll
    for (int i = 0; i < 4; ++i) {
        int idx = (i * 256 + tid) * 4;
        float4 wv = *(const float4*)(nw + idx);
        float4 bv = *(const float4*)(nb + idx);
        float4 r;
        r.x = v[i * 4 + 0]; r.y = v[i * 4 + 1]; r.z = v[i * 4 + 2]; r.w = v[i * 4 + 3];
        *(float4*)(resadd + base + idx) = r;
        ushort4 o;
        o.x = f2bf((r.x - mean) * rstd * wv.x + bv.x);
        o.y = f2bf((r.y - mean) * rstd * wv.y + bv.y);
        o.z = f2bf((r.z - mean) * rstd * wv.z + bv.z);
        o.w = f2bf((r.w - mean) * rstd * wv.w + bv.w);
        *(ushort4*)(lnout + base + idx) = o;
    }
}

// ---------------- fp32 -> bf16 weight cast ----------------
__global__ __launch_bounds__(256)
void cast_w(const float* __restrict__ w, unsigned short* __restrict__ o, long long n4) {
    long long i = (long long)blockIdx.x * 256 + threadIdx.x;
    if (i >= n4) return;
    float4 f = *(const float4*)(w + i * 4);
    ushort4 u;
    u.x = f2bf(f.x); u.y = f2bf(f.y); u.z = f2bf(f.z); u.w = f2bf(f.w);
    *(ushort4*)(o + i * 4) = u;
}

// ---------------- 256x256 bf16 GEMM, C = A * B^T, 8-phase read-ahead ----
// 512 threads = 8 waves (2M x 4N), per-wave 128x64 output.
// LDS 128 KiB: [slot][A/B][half 128 rows][64 cols] bf16, slot = tile & 1.
// 2 K-tiles per iteration, 8 phases. Phase p: {ds_reads for MFMA[p+1];
// stage 1 half-tile (2 gloads); [vmcnt(4) @ p4,p8]; s_barrier; setprio(1);
// 16 MFMA consuming phase p-1's reads; setprio(0)}. Reads cross one barrier
// before use -> LDS latency hidden under previous MFMA cluster + barrier.
// vmcnt gates always leave exactly the 2 newest half-tiles in flight; every
// staged region is barrier-separated from its last ds_read.
// REGISTER BUDGET (the R4 lesson): acc 128 + aq 32 + bq 64 + addr ~30 = ~254.
// __launch_bounds__(512, 1) -> 256 cap (8 waves/CU; LDS already limits to 1
// block/CU so this costs no occupancy). (512,2) capped the unified file at
// 128/wave -> total spill -> 2 GB scratch traffic, MfmaUtil 13.8%.
#define GBM 256
#define GBN 256
#define GBK 64

#define STAGE(s, mat, h, T) do {                                              \
    const unsigned short* _src = ((mat) ? pB : pA)                            \
        + (size_t)((h) * 128) * K + (size_t)(T) * 64;                         \
    char* _dst = ldsc + (s) * 65536 + (mat) * 32768 + (h) * 16384 + dOff;     \
    gload_lds16(_src, _dst);                                                  \
    gload_lds16(_src + (size_t)64 * K, _dst + 8192);                          \
} while (0)

#define RD_B(tb, s) do {                                                      \
    _Pragma("unroll")                                                         \
    for (int ni = 0; ni < 4; ++ni)                                            \
        _Pragma("unroll")                                                     \
        for (int kk = 0; kk < 2; ++kk)                                        \
            bq[tb][ni][kk] = *(const bf16x8*)(ldsc + (s) * 65536 + 32768      \
                + ((wc * 64 + ni * 16 + lrow) << 7) + ckk[kk]);               \
} while (0)

#define RD_A(ab, q, s) do {                                                   \
    _Pragma("unroll")                                                         \
    for (int m2 = 0; m2 < 2; ++m2)                                            \
        _Pragma("unroll")                                                     \
        for (int kk = 0; kk < 2; ++kk)                                        \
            aq[ab][m2][kk] = *(const bf16x8*)(ldsc + (s) * 65536              \
                + ((wr * 128 + ((q) * 2 + m2) * 16 + lrow) << 7) + ckk[kk]);  \
} while (0)

#define MF(q, ab, tb) do {                                                    \
    __builtin_amdgcn_s_setprio(1);                                            \
    _Pragma("unroll")                                                         \
    for (int m2 = 0; m2 < 2; ++m2)                                            \
        _Pragma("unroll")                                                     \
        for (int ni = 0; ni < 4; ++ni)                                        \
            _Pragma("unroll")                                                 \
            for (int kk = 0; kk < 2; ++kk)                                    \
                acc[(q) * 2 + m2][ni] = __builtin_amdgcn_mfma_f32_16x16x32_bf16( \
                    aq[ab][m2][kk], bq[tb][ni][kk], acc[(q) * 2 + m2][ni], 0, 0, 0); \
    __builtin_amdgcn_s_setprio(0);                                            \
} while (0)

#define BAR do { asm volatile("s_barrier" ::: "memory");                      \
                 __builtin_amdgcn_sched_barrier(0); } while (0)
#define GATE4 asm volatile("s_waitcnt vmcnt(4)" ::: "memory")
#define GATE0 asm volatile("s_waitcnt vmcnt(0)" ::: "memory")

template <int EPI>
__global__ __launch_bounds__(512, 1)
void gemm256(const unsigned short* __restrict__ A,
             const unsigned short* __restrict__ B,
             const float* __restrict__ bias_n,
             const float* __restrict__ resadd,
             void* __restrict__ Cout,
             int M, int N, int K) {
    __shared__ unsigned short lds[2][2][2][128 * 64];
    char* ldsc = (char*)&lds[0][0][0][0];
    const int tid = threadIdx.x;
    const int lane = tid & 63;
    const int w = tid >> 6;
    const int wr = w >> 2;   // 0..1
    const int wc = w & 3;    // 0..3

    const int nwg = gridDim.x;
    const int lg = (blockIdx.x & 7) * (nwg >> 3) + (blockIdx.x >> 3);
    const int nbx = N / GBN;
    const int brow = lg / nbx;
    const int bcol = lg % nbx;

    // staging source (pre-swizzled so linear LDS write = swizzled layout)
    const int srow = tid >> 3;                                   // 0..63
    const int scol = ((((tid & 7) << 4) ^ ((srow & 7) << 4)) >> 1);
    const unsigned short* pA = A + (size_t)(brow * GBM + srow) * K + scol;
    const unsigned short* pB = B + (size_t)(bcol * GBN + srow) * K + scol;
    const int dOff = tid * 16;

    // ds_read column bytes (swizzled), constant per lane
    const int lrow = lane & 15;
    int ckk[2];
    ckk[0] = (((lane >> 4) << 4)) ^ ((lrow & 7) << 4);
    ckk[1] = ckk[0] ^ 64;

    f32x4 acc[8][4] = {};
    bf16x8 aq[2][2][2];   // [bank][m2][kk]
    bf16x8 bq[2][4][2];   // [tile-parity][ni][kk]
    {
        bf16x8 z = {};
#pragma unroll
        for (int m2 = 0; m2 < 2; ++m2)
#pragma unroll
            for (int kk = 0; kk < 2; ++kk) aq[0][m2][kk] = z;
#pragma unroll
        for (int ni = 0; ni < 4; ++ni)
#pragma unroll
            for (int kk = 0; kk < 2; ++kk) bq[1][ni][kk] = z;
    }

    const int NT = K / GBK;
    const int niter = NT / 2;

    // prologue: tile0 (B0,B1,A0,A1) + tile1 (B0,B1); first 8 loads gated
    STAGE(0, 1, 0, 0); STAGE(0, 1, 1, 0);
    STAGE(0, 0, 0, 0); STAGE(0, 0, 1, 0);
    STAGE(1, 1, 0, 1); STAGE(1, 1, 1, 1);
    GATE4;
    BAR;

    for (int i = 0; i < niter - 1; ++i) {
        const int T0 = 2 * i, T1 = 2 * i + 1;
        // p1
        RD_B(0, 0); RD_A(1, 0, 0); STAGE(1, 0, 0, T1);           BAR; MF(3, 0, 1);
        // p2
        RD_A(0, 1, 0);              STAGE(1, 0, 1, T1);          BAR; MF(0, 1, 0);
        // p3
        RD_A(1, 2, 0);              STAGE(0, 1, 0, T0 + 2);      BAR; MF(1, 0, 0);
        // p4
        RD_A(0, 3, 0);              STAGE(0, 1, 1, T0 + 2); GATE4; BAR; MF(2, 1, 0);
        // p5
        RD_B(1, 1); RD_A(1, 0, 1);  STAGE(0, 0, 0, T0 + 2);      BAR; MF(3, 0, 0);
        // p6
        RD_A(0, 1, 1);              STAGE(0, 0, 1, T0 + 2);      BAR; MF(0, 1, 1);
        // p7
        RD_A(1, 2, 1);              STAGE(1, 1, 0, T1 + 2);      BAR; MF(1, 0, 1);
        // p8
        RD_A(0, 3, 1);              STAGE(1, 1, 1, T1 + 2); GATE4; BAR; MF(2, 1, 1);
    }
    {   // peeled final iteration (tiles NT-2, NT-1)
        const int T1 = NT - 1;
        RD_B(0, 0); RD_A(1, 0, 0); STAGE(1, 0, 0, T1);           BAR; MF(3, 0, 1);
        RD_A(0, 1, 0);              STAGE(1, 0, 1, T1);          BAR; MF(0, 1, 0);
        RD_A(1, 2, 0);                                           BAR; MF(1, 0, 0);
        RD_A(0, 3, 0);                                     GATE0; BAR; MF(2, 1, 0);
        RD_B(1, 1); RD_A(1, 0, 1);                               BAR; MF(3, 0, 0);
        RD_A(0, 1, 1);                                           BAR; MF(0, 1, 1);
        RD_A(1, 2, 1);                                           BAR; MF(1, 0, 1);
        RD_A(0, 3, 1);                                           BAR; MF(2, 1, 1);
        MF(3, 0, 1);  // trailing q3 of tile NT-1
    }

    // epilogue: C/D layout col = lane&15, row = (lane>>4)*4 + j
    const int c0 = bcol * GBN + wc * 64 + lrow;
    const int r0 = brow * GBM + wr * 128 + (lane >> 4) * 4;
#pragma unroll
    for (int mi = 0; mi < 8; ++mi) {
#pragma unroll
        for (int j = 0; j < 4; ++j) {
            const int row = r0 + mi * 16 + j;
#pragma unroll
            for (int ni = 0; ni < 4; ++ni) {
                const int col = c0 + ni * 16;
                float x = acc[mi][ni][j] + bias_n[col];
                if (EPI == 0) {
                    ((unsigned short*)Cout)[(size_t)row * N + col] = f2bf(gelu_tanh(x));
                } else {
                    const size_t off = (size_t)row * N + col;
                    ((float*)Cout)[off] = x + resadd[off];
                }
            }
        }
    }
}

extern "C" void kernel_launch(void* const* d_in, const int* in_sizes, int n_in,
                              void* d_out, int out_size, void* d_ws, size_t ws_size,
                              hipStream_t stream) {
    const float* input    = (const float*)d_in[0];
    const float* residual = (const float*)d_in[1];
    const float* bias     = (const float*)d_in[2];
    const float* attn_nw  = (const float*)d_in[3];
    const float* attn_nb  = (const float*)d_in[4];
    const float* inter_w  = (const float*)d_in[5];
    const float* inter_b  = (const float*)d_in[6];
    const float* output_w = (const float*)d_in[7];
    const float* output_b = (const float*)d_in[8];

    const int H = in_sizes[3];            // 4096
    const int I = in_sizes[6];            // 16384
    const int T = in_sizes[0] / H;        // B*S = 4096

    char* ws = (char*)d_ws;
    float* resadd      = (float*)ws;
    unsigned short* ln = (unsigned short*)(ws + (size_t)T * H * 4);
    unsigned short* w1 = (unsigned short*)((char*)ln + (size_t)T * H * 2);
    unsigned short* w2 = w1 + (size_t)I * H;
    unsigned short* act = w2 + (size_t)H * I;

    fused_add_ln<<<T, 256, 0, stream>>>(input, residual, bias, attn_nw, attn_nb,
                                        resadd, ln, H);

    {
        long long n4 = (long long)I * H / 4;
        int blocks = (int)((n4 + 255) / 256);
        cast_w<<<blocks, 256, 0, stream>>>(inter_w, w1, n4);
        cast_w<<<blocks, 256, 0, stream>>>(output_w, w2, n4);
    }

    // GEMM1: act = gelu(ln @ inter_w^T + inter_b)   [T,I]
    {
        dim3 grid((T / GBM) * (I / GBN));
        gemm256<0><<<grid, 512, 0, stream>>>(ln, w1, inter_b, nullptr, act, T, I, H);
    }

    // GEMM2: out = act @ output_w^T + output_b + resadd   [T,H]
    {
        dim3 grid((T / GBM) * (H / GBN));
        gemm256<1><<<grid, 512, 0, stream>>>(act, w2, output_b, resadd, d_out, T, H, I);
    }
}

// Round 6
// 3219.839 us; speedup vs baseline: 1.0020x; 1.0016x over previous
//
#include <hip/hip_runtime.h>
#include <hip/hip_bf16.h>
#include <cstdint>
#include <math.h>

typedef __attribute__((ext_vector_type(4))) float f32x4;
typedef __attribute__((ext_vector_type(8))) __bf16 bf16x8;

__device__ __forceinline__ unsigned short f2bf(float f) {
    union { float f; unsigned u; } v; v.f = f;
    unsigned u = v.u + 0x7fffu + ((v.u >> 16) & 1u);
    return (unsigned short)(u >> 16);
}

__device__ __forceinline__ float gelu_tanh(float x) {
    float x3 = x * x * x;
    float t = tanhf(0.7978845608028654f * (x + 0.044715f * x3));
    return 0.5f * x * (1.0f + t);
}

__device__ __forceinline__ void gload_lds16(const void* g, void* l) {
    __builtin_amdgcn_global_load_lds(
        (__attribute__((address_space(1))) void*)(uintptr_t)g,
        (__attribute__((address_space(3))) void*)(unsigned)(uintptr_t)l,
        16, 0, 0);
}

// ---------------- fused bias-add + residual + LayerNorm ----------------
__global__ __launch_bounds__(256)
void fused_add_ln(const float* __restrict__ in, const float* __restrict__ res,
                  const float* __restrict__ bias, const float* __restrict__ nw,
                  const float* __restrict__ nb, float* __restrict__ resadd,
                  unsigned short* __restrict__ lnout, int H) {
    const int row = blockIdx.x;
    const int tid = threadIdx.x;
    const size_t base = (size_t)row * H;
    float v[16];
    float s = 0.f, ss = 0.f;
#pragma unroll
    for (int i = 0; i < 4; ++i) {
        int idx = (i * 256 + tid) * 4;
        float4 a = *(const float4*)(in + base + idx);
        float4 b = *(const float4*)(res + base + idx);
        float4 c = *(const float4*)(bias + idx);
        float x0 = a.x + b.x + c.x, x1 = a.y + b.y + c.y;
        float x2 = a.z + b.z + c.z, x3 = a.w + b.w + c.w;
        v[i * 4 + 0] = x0; v[i * 4 + 1] = x1; v[i * 4 + 2] = x2; v[i * 4 + 3] = x3;
        s += x0 + x1 + x2 + x3;
        ss += x0 * x0 + x1 * x1 + x2 * x2 + x3 * x3;
    }
#pragma unroll
    for (int off = 32; off > 0; off >>= 1) {
        s += __shfl_down(s, off);
        ss += __shfl_down(ss, off);
    }
    __shared__ float red[8];
    const int w = tid >> 6;
    if ((tid & 63) == 0) { red[w] = s; red[4 + w] = ss; }
    __syncthreads();
    s = red[0] + red[1] + red[2] + red[3];
    ss = red[4] + red[5] + red[6] + red[7];
    const float mean = s / H;
    const float var = ss / H - mean * mean;
    const float rstd = rsqrtf(var + 1e-12f);
#pragma unroll
    for (int i = 0; i < 4; ++i) {
        int idx = (i * 256 + tid) * 4;
        float4 wv = *(const float4*)(nw + idx);
        float4 bv = *(const float4*)(nb + idx);
        float4 r;
        r.x = v[i * 4 + 0]; r.y = v[i * 4 + 1]; r.z = v[i * 4 + 2]; r.w = v[i * 4 + 3];
        *(float4*)(resadd + base + idx) = r;
        ushort4 o;
        o.x = f2bf((r.x - mean) * rstd * wv.x + bv.x);
        o.y = f2bf((r.y - mean) * rstd * wv.y + bv.y);
        o.z = f2bf((r.z - mean) * rstd * wv.z + bv.z);
        o.w = f2bf((r.w - mean) * rstd * wv.w + bv.w);
        *(ushort4*)(lnout + base + idx) = o;
    }
}

// ---------------- fp32 -> bf16 weight cast ----------------
__global__ __launch_bounds__(256)
void cast_w(const float* __restrict__ w, unsigned short* __restrict__ o, long long n4) {
    long long i = (long long)blockIdx.x * 256 + threadIdx.x;
    if (i >= n4) return;
    float4 f = *(const float4*)(w + i * 4);
    ushort4 u;
    u.x = f2bf(f.x); u.y = f2bf(f.y); u.z = f2bf(f.z); u.w = f2bf(f.w);
    *(ushort4*)(o + i * 4) = u;
}

// ---------------- 256x256 bf16 GEMM, C = A * B^T, 8-phase read-ahead ----
// 512 threads = 8 waves (2M x 4N), per-wave 128x64 output.
// LDS 128 KiB: [slot][A/B][half 128 rows][64 cols] bf16, slot = tile & 1.
// 2 K-tiles per iteration, 8 phases. Phase p: {ds_reads for MFMA[p+1];
// stage 1 half-tile (2 gloads); [vmcnt(4) @ p4,p8]; s_barrier; setprio(1);
// 16 MFMA consuming phase p-1's reads; setprio(0)}. Reads cross one barrier
// before use -> LDS latency hidden under previous MFMA cluster + barrier.
// vmcnt gates always leave exactly the 2 newest half-tiles in flight; every
// staged region is barrier-separated from its last ds_read.
//
// REGISTER BUDGET (R4/R5 lesson): demand ~250 (acc 128 + aq 32 + bq 64 peak
// + ~25 transients). __launch_bounds__'s 2nd arg only sets the occupancy
// FLOOR; the scheduler still targets its own (LDS-blind) max occupancy of
// 4 waves/EU -> 128-reg budget -> ~126 regs spilled -> 2 GB scratch traffic,
// MfmaUtil 13.8% (R4=R5 bit-identical). Fix: amdgpu_waves_per_eu(2,2) pins
// target occupancy to exactly 2 waves/EU (all LDS permits: 1 block/CU x 8
// waves) -> 256-reg budget -> fits. 2/EU is also required for launchability
// at 256 regs (512-thr block needs 8 wave slots on its CU).
#define GBM 256
#define GBN 256
#define GBK 64

#define STAGE(s, mat, h, T) do {                                              \
    const unsigned short* _src = ((mat) ? pB : pA)                            \
        + (size_t)((h) * 128) * K + (size_t)(T) * 64;                         \
    char* _dst = ldsc + (s) * 65536 + (mat) * 32768 + (h) * 16384 + dOff;     \
    gload_lds16(_src, _dst);                                                  \
    gload_lds16(_src + (size_t)64 * K, _dst + 8192);                          \
} while (0)

#define RD_B(tb, s) do {                                                      \
    _Pragma("unroll")                                                         \
    for (int ni = 0; ni < 4; ++ni)                                            \
        _Pragma("unroll")                                                     \
        for (int kk = 0; kk < 2; ++kk)                                        \
            bq[tb][ni][kk] = *(const bf16x8*)(ldsc + (s) * 65536 + 32768      \
                + ((wc * 64 + ni * 16 + lrow) << 7) + ckk[kk]);               \
} while (0)

#define RD_A(ab, q, s) do {                                                   \
    _Pragma("unroll")                                                         \
    for (int m2 = 0; m2 < 2; ++m2)                                            \
        _Pragma("unroll")                                                     \
        for (int kk = 0; kk < 2; ++kk)                                        \
            aq[ab][m2][kk] = *(const bf16x8*)(ldsc + (s) * 65536              \
                + ((wr * 128 + ((q) * 2 + m2) * 16 + lrow) << 7) + ckk[kk]);  \
} while (0)

#define MF(q, ab, tb) do {                                                    \
    __builtin_amdgcn_s_setprio(1);                                            \
    _Pragma("unroll")                                                         \
    for (int m2 = 0; m2 < 2; ++m2)                                            \
        _Pragma("unroll")                                                     \
        for (int ni = 0; ni < 4; ++ni)                                        \
            _Pragma("unroll")                                                 \
            for (int kk = 0; kk < 2; ++kk)                                    \
                acc[(q) * 2 + m2][ni] = __builtin_amdgcn_mfma_f32_16x16x32_bf16( \
                    aq[ab][m2][kk], bq[tb][ni][kk], acc[(q) * 2 + m2][ni], 0, 0, 0); \
    __builtin_amdgcn_s_setprio(0);                                            \
} while (0)

#define BAR do { asm volatile("s_barrier" ::: "memory");                      \
                 __builtin_amdgcn_sched_barrier(0); } while (0)
#define GATE4 asm volatile("s_waitcnt vmcnt(4)" ::: "memory")
#define GATE0 asm volatile("s_waitcnt vmcnt(0)" ::: "memory")

template <int EPI>
__global__
__attribute__((amdgpu_flat_work_group_size(512, 512)))
__attribute__((amdgpu_waves_per_eu(2, 2)))
void gemm256(const unsigned short* __restrict__ A,
             const unsigned short* __restrict__ B,
             const float* __restrict__ bias_n,
             const float* __restrict__ resadd,
             void* __restrict__ Cout,
             int M, int N, int K) {
    __shared__ unsigned short lds[2][2][2][128 * 64];
    char* ldsc = (char*)&lds[0][0][0][0];
    const int tid = threadIdx.x;
    const int lane = tid & 63;
    const int w = tid >> 6;
    const int wr = w >> 2;   // 0..1
    const int wc = w & 3;    // 0..3

    const int nwg = gridDim.x;
    const int lg = (blockIdx.x & 7) * (nwg >> 3) + (blockIdx.x >> 3);
    const int nbx = N / GBN;
    const int brow = lg / nbx;
    const int bcol = lg % nbx;

    // staging source (pre-swizzled so linear LDS write = swizzled layout)
    const int srow = tid >> 3;                                   // 0..63
    const int scol = ((((tid & 7) << 4) ^ ((srow & 7) << 4)) >> 1);
    const unsigned short* pA = A + (size_t)(brow * GBM + srow) * K + scol;
    const unsigned short* pB = B + (size_t)(bcol * GBN + srow) * K + scol;
    const int dOff = tid * 16;

    // ds_read column bytes (swizzled), constant per lane
    const int lrow = lane & 15;
    int ckk[2];
    ckk[0] = (((lane >> 4) << 4)) ^ ((lrow & 7) << 4);
    ckk[1] = ckk[0] ^ 64;

    f32x4 acc[8][4] = {};
    bf16x8 aq[2][2][2];   // [bank][m2][kk]
    bf16x8 bq[2][4][2];   // [tile-parity][ni][kk]
    {
        bf16x8 z = {};
#pragma unroll
        for (int m2 = 0; m2 < 2; ++m2)
#pragma unroll
            for (int kk = 0; kk < 2; ++kk) aq[0][m2][kk] = z;
#pragma unroll
        for (int ni = 0; ni < 4; ++ni)
#pragma unroll
            for (int kk = 0; kk < 2; ++kk) bq[1][ni][kk] = z;
    }

    const int NT = K / GBK;
    const int niter = NT / 2;

    // prologue: tile0 (B0,B1,A0,A1) + tile1 (B0,B1); first 8 loads gated
    STAGE(0, 1, 0, 0); STAGE(0, 1, 1, 0);
    STAGE(0, 0, 0, 0); STAGE(0, 0, 1, 0);
    STAGE(1, 1, 0, 1); STAGE(1, 1, 1, 1);
    GATE4;
    BAR;

    for (int i = 0; i < niter - 1; ++i) {
        const int T0 = 2 * i, T1 = 2 * i + 1;
        // p1
        RD_B(0, 0); RD_A(1, 0, 0); STAGE(1, 0, 0, T1);           BAR; MF(3, 0, 1);
        // p2
        RD_A(0, 1, 0);              STAGE(1, 0, 1, T1);          BAR; MF(0, 1, 0);
        // p3
        RD_A(1, 2, 0);              STAGE(0, 1, 0, T0 + 2);      BAR; MF(1, 0, 0);
        // p4
        RD_A(0, 3, 0);              STAGE(0, 1, 1, T0 + 2); GATE4; BAR; MF(2, 1, 0);
        // p5
        RD_B(1, 1); RD_A(1, 0, 1);  STAGE(0, 0, 0, T0 + 2);      BAR; MF(3, 0, 0);
        // p6
        RD_A(0, 1, 1);              STAGE(0, 0, 1, T0 + 2);      BAR; MF(0, 1, 1);
        // p7
        RD_A(1, 2, 1);              STAGE(1, 1, 0, T1 + 2);      BAR; MF(1, 0, 1);
        // p8
        RD_A(0, 3, 1);              STAGE(1, 1, 1, T1 + 2); GATE4; BAR; MF(2, 1, 1);
    }
    {   // peeled final iteration (tiles NT-2, NT-1)
        const int T1 = NT - 1;
        RD_B(0, 0); RD_A(1, 0, 0); STAGE(1, 0, 0, T1);           BAR; MF(3, 0, 1);
        RD_A(0, 1, 0);              STAGE(1, 0, 1, T1);          BAR; MF(0, 1, 0);
        RD_A(1, 2, 0);                                           BAR; MF(1, 0, 0);
        RD_A(0, 3, 0);                                     GATE0; BAR; MF(2, 1, 0);
        RD_B(1, 1); RD_A(1, 0, 1);                               BAR; MF(3, 0, 0);
        RD_A(0, 1, 1);                                           BAR; MF(0, 1, 1);
        RD_A(1, 2, 1);                                           BAR; MF(1, 0, 1);
        RD_A(0, 3, 1);                                           BAR; MF(2, 1, 1);
        MF(3, 0, 1);  // trailing q3 of tile NT-1
    }

    // epilogue: C/D layout col = lane&15, row = (lane>>4)*4 + j
    const int c0 = bcol * GBN + wc * 64 + lrow;
    const int r0 = brow * GBM + wr * 128 + (lane >> 4) * 4;
#pragma unroll
    for (int mi = 0; mi < 8; ++mi) {
#pragma unroll
        for (int j = 0; j < 4; ++j) {
            const int row = r0 + mi * 16 + j;
#pragma unroll
            for (int ni = 0; ni < 4; ++ni) {
                const int col = c0 + ni * 16;
                float x = acc[mi][ni][j] + bias_n[col];
                if (EPI == 0) {
                    ((unsigned short*)Cout)[(size_t)row * N + col] = f2bf(gelu_tanh(x));
                } else {
                    const size_t off = (size_t)row * N + col;
                    ((float*)Cout)[off] = x + resadd[off];
                }
            }
        }
    }
}

extern "C" void kernel_launch(void* const* d_in, const int* in_sizes, int n_in,
                              void* d_out, int out_size, void* d_ws, size_t ws_size,
                              hipStream_t stream) {
    const float* input    = (const float*)d_in[0];
    const float* residual = (const float*)d_in[1];
    const float* bias     = (const float*)d_in[2];
    const float* attn_nw  = (const float*)d_in[3];
    const float* attn_nb  = (const float*)d_in[4];
    const float* inter_w  = (const float*)d_in[5];
    const float* inter_b  = (const float*)d_in[6];
    const float* output_w = (const float*)d_in[7];
    const float* output_b = (const float*)d_in[8];

    const int H = in_sizes[3];            // 4096
    const int I = in_sizes[6];            // 16384
    const int T = in_sizes[0] / H;        // B*S = 4096

    char* ws = (char*)d_ws;
    float* resadd      = (float*)ws;
    unsigned short* ln = (unsigned short*)(ws + (size_t)T * H * 4);
    unsigned short* w1 = (unsigned short*)((char*)ln + (size_t)T * H * 2);
    unsigned short* w2 = w1 + (size_t)I * H;
    unsigned short* act = w2 + (size_t)H * I;

    fused_add_ln<<<T, 256, 0, stream>>>(input, residual, bias, attn_nw, attn_nb,
                                        resadd, ln, H);

    {
        long long n4 = (long long)I * H / 4;
        int blocks = (int)((n4 + 255) / 256);
        cast_w<<<blocks, 256, 0, stream>>>(inter_w, w1, n4);
        cast_w<<<blocks, 256, 0, stream>>>(output_w, w2, n4);
    }

    // GEMM1: act = gelu(ln @ inter_w^T + inter_b)   [T,I]
    {
        dim3 grid((T / GBM) * (I / GBN));
        gemm256<0><<<grid, 512, 0, stream>>>(ln, w1, inter_b, nullptr, act, T, I, H);
    }

    // GEMM2: out = act @ output_w^T + output_b + resadd   [T,H]
    {
        dim3 grid((T / GBM) * (H / GBN));
        gemm256<1><<<grid, 512, 0, stream>>>(act, w2, output_b, resadd, d_out, T, H, I);
    }
}

// Round 7
// 1120.487 us; speedup vs baseline: 2.8793x; 2.8736x over previous
//
#include <hip/hip_runtime.h>
#include <hip/hip_bf16.h>
#include <cstdint>
#include <math.h>

typedef __attribute__((ext_vector_type(4))) float f32x4;
typedef __attribute__((ext_vector_type(8))) __bf16 bf16x8;

__device__ __forceinline__ unsigned short f2bf(float f) {
    union { float f; unsigned u; } v; v.f = f;
    unsigned u = v.u + 0x7fffu + ((v.u >> 16) & 1u);
    return (unsigned short)(u >> 16);
}

__device__ __forceinline__ float gelu_tanh(float x) {
    float x3 = x * x * x;
    float t = tanhf(0.7978845608028654f * (x + 0.044715f * x3));
    return 0.5f * x * (1.0f + t);
}

__device__ __forceinline__ void gload_lds16(const void* g, void* l) {
    __builtin_amdgcn_global_load_lds(
        (__attribute__((address_space(1))) void*)(uintptr_t)g,
        (__attribute__((address_space(3))) void*)(unsigned)(uintptr_t)l,
        16, 0, 0);
}

// ---------------- fused bias-add + residual + LayerNorm ----------------
__global__ __launch_bounds__(256)
void fused_add_ln(const float* __restrict__ in, const float* __restrict__ res,
                  const float* __restrict__ bias, const float* __restrict__ nw,
                  const float* __restrict__ nb, float* __restrict__ resadd,
                  unsigned short* __restrict__ lnout, int H) {
    const int row = blockIdx.x;
    const int tid = threadIdx.x;
    const size_t base = (size_t)row * H;
    float v[16];
    float s = 0.f, ss = 0.f;
#pragma unroll
    for (int i = 0; i < 4; ++i) {
        int idx = (i * 256 + tid) * 4;
        float4 a = *(const float4*)(in + base + idx);
        float4 b = *(const float4*)(res + base + idx);
        float4 c = *(const float4*)(bias + idx);
        float x0 = a.x + b.x + c.x, x1 = a.y + b.y + c.y;
        float x2 = a.z + b.z + c.z, x3 = a.w + b.w + c.w;
        v[i * 4 + 0] = x0; v[i * 4 + 1] = x1; v[i * 4 + 2] = x2; v[i * 4 + 3] = x3;
        s += x0 + x1 + x2 + x3;
        ss += x0 * x0 + x1 * x1 + x2 * x2 + x3 * x3;
    }
#pragma unroll
    for (int off = 32; off > 0; off >>= 1) {
        s += __shfl_down(s, off);
        ss += __shfl_down(ss, off);
    }
    __shared__ float red[8];
    const int w = tid >> 6;
    if ((tid & 63) == 0) { red[w] = s; red[4 + w] = ss; }
    __syncthreads();
    s = red[0] + red[1] + red[2] + red[3];
    ss = red[4] + red[5] + red[6] + red[7];
    const float mean = s / H;
    const float var = ss / H - mean * mean;
    const float rstd = rsqrtf(var + 1e-12f);
#pragma unroll
    for (int i = 0; i < 4; ++i) {
        int idx = (i * 256 + tid) * 4;
        float4 wv = *(const float4*)(nw + idx);
        float4 bv = *(const float4*)(nb + idx);
        float4 r;
        r.x = v[i * 4 + 0]; r.y = v[i * 4 + 1]; r.z = v[i * 4 + 2]; r.w = v[i * 4 + 3];
        *(float4*)(resadd + base + idx) = r;
        ushort4 o;
        o.x = f2bf((r.x - mean) * rstd * wv.x + bv.x);
        o.y = f2bf((r.y - mean) * rstd * wv.y + bv.y);
        o.z = f2bf((r.z - mean) * rstd * wv.z + bv.z);
        o.w = f2bf((r.w - mean) * rstd * wv.w + bv.w);
        *(ushort4*)(lnout + base + idx) = o;
    }
}

// ---------------- fp32 -> bf16 weight cast ----------------
__global__ __launch_bounds__(256)
void cast_w(const float* __restrict__ w, unsigned short* __restrict__ o, long long n4) {
    long long i = (long long)blockIdx.x * 256 + threadIdx.x;
    if (i >= n4) return;
    float4 f = *(const float4*)(w + i * 4);
    ushort4 u;
    u.x = f2bf(f.x); u.y = f2bf(f.y); u.z = f2bf(f.z); u.w = f2bf(f.w);
    *(ushort4*)(o + i * 4) = u;
}

// ------------- 256x256 bf16 GEMM, C = A * B^T, m201-faithful 8-phase ----
// 512 threads = 8 waves (2M x 4N), per-wave 128x64.  LDS 128 KiB.
// KEY FIX vs R4-R6: fragments are PHASE-LOCAL (ds_read and its consuming
// MFMA in the SAME phase, separated by the barrier which absorbs LDS
// latency). Only bq (32 regs) persists 4 phases. Arch-VGPR demand ~88
// within the hard 128 budget (512-thr block => 256 total cap, acc=128 AGPR).
// Phase: {RD_B(q0 only) + RD_A(q); STAGE 1 half; [vmcnt(4) @p4,p8]; bar;
//         lgkm(0)+schedbar; setprio(1); 16 MFMA(q); setprio(0); bar}
// Stage order p1..p8: A0(s1,T1) A1(s1,T1) B0(s0,T0+2) B1(s0,T0+2)
//                     A0(s0,T0+2) A1(s0,T0+2) B0(s1,T1+2) B1(s1,T1+2)
// Clobber-proof: each stage issues after its region's last reader's
// closing barrier (B[s] read only at its tile's q0 phase; A[s] last read
// at q3). Landing-proof: vmcnt(4) leaves exactly the 2 newest halves in
// flight; p1/p5 reads only touch halves staged >=2 gates ago.
#define GBM 256
#define GBN 256
#define GBK 64

#define STAGE(s, mat, h, T) do {                                              \
    const unsigned short* _src = ((mat) ? pB : pA)                            \
        + (size_t)((h) * 128) * K + (size_t)(T) * 64;                         \
    char* _dst = ldsc + (s) * 65536 + (mat) * 32768 + (h) * 16384 + dOff;     \
    gload_lds16(_src, _dst);                                                  \
    gload_lds16(_src + (size_t)64 * K, _dst + 8192);                          \
} while (0)

#define RD_B(s) do {                                                          \
    _Pragma("unroll")                                                         \
    for (int ni = 0; ni < 4; ++ni)                                            \
        _Pragma("unroll")                                                     \
        for (int kk = 0; kk < 2; ++kk)                                        \
            bq[ni][kk] = *(const bf16x8*)(ldsc + (s) * 65536 + 32768          \
                + ((wc * 64 + ni * 16 + lrow) << 7) + ckk[kk]);               \
} while (0)

#define RD_A(q, s) do {                                                       \
    _Pragma("unroll")                                                         \
    for (int m2 = 0; m2 < 2; ++m2)                                            \
        _Pragma("unroll")                                                     \
        for (int kk = 0; kk < 2; ++kk)                                        \
            aq[m2][kk] = *(const bf16x8*)(ldsc + (s) * 65536                  \
                + ((wr * 128 + ((q) * 2 + m2) * 16 + lrow) << 7) + ckk[kk]);  \
} while (0)

#define BAR asm volatile("s_barrier" ::: "memory")
#define GATE4 asm volatile("s_waitcnt vmcnt(4)" ::: "memory")
#define GATE0 asm volatile("s_waitcnt vmcnt(0)" ::: "memory")
#define NOGATE

// one phase: reads (+B at q0), stage stmt, optional gate, bar, wait, MFMA, bar
#define PHASE(q, s, STG, GT) do {                                             \
    if ((q) == 0) RD_B(s);                                                    \
    RD_A(q, s);                                                               \
    STG;                                                                      \
    GT;                                                                       \
    BAR;                                                                      \
    asm volatile("s_waitcnt lgkmcnt(0)" ::: "memory");                        \
    __builtin_amdgcn_sched_barrier(0);                                        \
    __builtin_amdgcn_s_setprio(1);                                            \
    _Pragma("unroll")                                                         \
    for (int m2 = 0; m2 < 2; ++m2)                                            \
        _Pragma("unroll")                                                     \
        for (int ni = 0; ni < 4; ++ni)                                        \
            _Pragma("unroll")                                                 \
            for (int kk = 0; kk < 2; ++kk)                                    \
                acc[(q) * 2 + m2][ni] = __builtin_amdgcn_mfma_f32_16x16x32_bf16( \
                    aq[m2][kk], bq[ni][kk], acc[(q) * 2 + m2][ni], 0, 0, 0);  \
    __builtin_amdgcn_s_setprio(0);                                            \
    BAR;                                                                      \
} while (0)

template <int EPI>
__global__ __launch_bounds__(512, 2)
void gemm256(const unsigned short* __restrict__ A,
             const unsigned short* __restrict__ B,
             const float* __restrict__ bias_n,
             const float* __restrict__ resadd,
             void* __restrict__ Cout,
             int M, int N, int K) {
    __shared__ unsigned short lds[2][2][2][128 * 64];  // [slot][A/B][half][.]
    char* ldsc = (char*)&lds[0][0][0][0];
    const int tid = threadIdx.x;
    const int lane = tid & 63;
    const int w = tid >> 6;
    const int wr = w >> 2;   // 0..1
    const int wc = w & 3;    // 0..3

    const int nwg = gridDim.x;
    const int lg = (blockIdx.x & 7) * (nwg >> 3) + (blockIdx.x >> 3);
    const int nbx = N / GBN;
    const int brow = lg / nbx;
    const int bcol = lg % nbx;

    // staging source (pre-swizzled so linear LDS write = swizzled layout)
    const int srow = tid >> 3;                                   // 0..63
    const int scol = ((((tid & 7) << 4) ^ ((srow & 7) << 4)) >> 1);
    const unsigned short* pA = A + (size_t)(brow * GBM + srow) * K + scol;
    const unsigned short* pB = B + (size_t)(bcol * GBN + srow) * K + scol;
    const int dOff = tid * 16;

    // ds_read column bytes (swizzled), constant per lane
    const int lrow = lane & 15;
    int ckk[2];
    ckk[0] = (((lane >> 4) << 4)) ^ ((lrow & 7) << 4);
    ckk[1] = ckk[0] ^ 64;

    f32x4 acc[8][4] = {};
    bf16x8 aq[2][2];   // phase-local A fragments
    bf16x8 bq[4][2];   // per-tile B fragments (live q0..q3)

    const int NT = K / GBK;
    const int niter = NT / 2;

    // prologue: B+A halves of tile0 (slot0), B halves of tile1 (slot1)
    STAGE(0, 1, 0, 0); STAGE(0, 1, 1, 0);
    STAGE(0, 0, 0, 0); STAGE(0, 0, 1, 0);
    STAGE(1, 1, 0, 1); STAGE(1, 1, 1, 1);
    GATE4;   // tile0 fully landed; tile1 B halves may remain in flight
    BAR;

    for (int i = 0; i < niter - 1; ++i) {
        const int T0 = 2 * i, T1 = 2 * i + 1;
        PHASE(0, 0, STAGE(1, 0, 0, T1),     NOGATE);
        PHASE(1, 0, STAGE(1, 0, 1, T1),     NOGATE);
        PHASE(2, 0, STAGE(0, 1, 0, T0 + 2), NOGATE);
        PHASE(3, 0, STAGE(0, 1, 1, T0 + 2), GATE4);
        PHASE(0, 1, STAGE(0, 0, 0, T0 + 2), NOGATE);
        PHASE(1, 1, STAGE(0, 0, 1, T0 + 2), NOGATE);
        PHASE(2, 1, STAGE(1, 1, 0, T1 + 2), NOGATE);
        PHASE(3, 1, STAGE(1, 1, 1, T1 + 2), GATE4);
    }
    {   // last iteration: only stage A halves of T1; drain gates
        const int T1 = NT - 1;
        PHASE(0, 0, STAGE(1, 0, 0, T1), NOGATE);
        PHASE(1, 0, STAGE(1, 0, 1, T1), NOGATE);
        PHASE(2, 0, NOGATE,             NOGATE);
        PHASE(3, 0, NOGATE,             GATE0);
        PHASE(0, 1, NOGATE,             NOGATE);
        PHASE(1, 1, NOGATE,             NOGATE);
        PHASE(2, 1, NOGATE,             NOGATE);
        PHASE(3, 1, NOGATE,             NOGATE);
    }

    // epilogue: C/D layout col = lane&15, row = (lane>>4)*4 + j
    const int c0 = bcol * GBN + wc * 64 + lrow;
    const int r0 = brow * GBM + wr * 128 + (lane >> 4) * 4;
#pragma unroll
    for (int mi = 0; mi < 8; ++mi) {
#pragma unroll
        for (int j = 0; j < 4; ++j) {
            const int row = r0 + mi * 16 + j;
#pragma unroll
            for (int ni = 0; ni < 4; ++ni) {
                const int col = c0 + ni * 16;
                float x = acc[mi][ni][j] + bias_n[col];
                if (EPI == 0) {
                    ((unsigned short*)Cout)[(size_t)row * N + col] = f2bf(gelu_tanh(x));
                } else {
                    const size_t off = (size_t)row * N + col;
                    ((float*)Cout)[off] = x + resadd[off];
                }
            }
        }
    }
}

extern "C" void kernel_launch(void* const* d_in, const int* in_sizes, int n_in,
                              void* d_out, int out_size, void* d_ws, size_t ws_size,
                              hipStream_t stream) {
    const float* input    = (const float*)d_in[0];
    const float* residual = (const float*)d_in[1];
    const float* bias     = (const float*)d_in[2];
    const float* attn_nw  = (const float*)d_in[3];
    const float* attn_nb  = (const float*)d_in[4];
    const float* inter_w  = (const float*)d_in[5];
    const float* inter_b  = (const float*)d_in[6];
    const float* output_w = (const float*)d_in[7];
    const float* output_b = (const float*)d_in[8];

    const int H = in_sizes[3];            // 4096
    const int I = in_sizes[6];            // 16384
    const int T = in_sizes[0] / H;        // B*S = 4096

    char* ws = (char*)d_ws;
    float* resadd      = (float*)ws;
    unsigned short* ln = (unsigned short*)(ws + (size_t)T * H * 4);
    unsigned short* w1 = (unsigned short*)((char*)ln + (size_t)T * H * 2);
    unsigned short* w2 = w1 + (size_t)I * H;
    unsigned short* act = w2 + (size_t)H * I;

    fused_add_ln<<<T, 256, 0, stream>>>(input, residual, bias, attn_nw, attn_nb,
                                        resadd, ln, H);

    {
        long long n4 = (long long)I * H / 4;
        int blocks = (int)((n4 + 255) / 256);
        cast_w<<<blocks, 256, 0, stream>>>(inter_w, w1, n4);
        cast_w<<<blocks, 256, 0, stream>>>(output_w, w2, n4);
    }

    // GEMM1: act = gelu(ln @ inter_w^T + inter_b)   [T,I]
    {
        dim3 grid((T / GBM) * (I / GBN));
        gemm256<0><<<grid, 512, 0, stream>>>(ln, w1, inter_b, nullptr, act, T, I, H);
    }

    // GEMM2: out = act @ output_w^T + output_b + resadd   [T,H]
    {
        dim3 grid((T / GBM) * (H / GBN));
        gemm256<1><<<grid, 512, 0, stream>>>(act, w2, output_b, resadd, d_out, T, H, I);
    }
}